// Round 20
// baseline (189.943 us; speedup 1.0000x reference)
//
#include <hip/hip_runtime.h>

typedef _Float16 f16;
typedef _Float16 h4 __attribute__((ext_vector_type(4)));
typedef _Float16 h8 __attribute__((ext_vector_type(8)));
typedef float f4 __attribute__((ext_vector_type(4)));

typedef const __attribute__((address_space(1))) char gchar;
typedef __attribute__((address_space(3))) char lchar;

#define B_ 4
#define S_ 2048
#define D_ 1024
#define H_ 1024

template <int N>
__device__ __forceinline__ void vmwait() {
  if constexpr (N == 0) asm volatile("s_waitcnt vmcnt(0)" ::: "memory");
  else if constexpr (N == 6) asm volatile("s_waitcnt vmcnt(6)" ::: "memory");
}

// ---------------- prep: cast x1,x2,x3,Wv (16 elems/thread) + transpose-cast Wq,Wk ----------------
__global__ __launch_bounds__(256) void prep(
    const float* __restrict__ x1, const float* __restrict__ x2, const float* __restrict__ x3,
    const float* __restrict__ wv, const float* __restrict__ wq, const float* __restrict__ wk,
    f16* __restrict__ o1, f16* __restrict__ o2, f16* __restrict__ o3, f16* __restrict__ ow,
    f16* __restrict__ oqT, f16* __restrict__ okT) {
  const int bx = blockIdx.x;
  const int tid = threadIdx.x;
  if (bx < 6400) {
    const long g = bx * 256L + tid;
    const float* in;
    f16* out;
    long off;
    if (g < (3L << 19)) {
      const int w = (int)(g >> 19);
      off = (g & ((1L << 19) - 1)) * 16;
      in = w == 0 ? x1 : (w == 1 ? x2 : x3);
      out = w == 0 ? o1 : (w == 1 ? o2 : o3);
    } else {
      off = (g - (3L << 19)) * 16;
      in = wv;
      out = ow;
    }
    float4 a = *(const float4*)(in + off);
    float4 b = *(const float4*)(in + off + 4);
    float4 c = *(const float4*)(in + off + 8);
    float4 d = *(const float4*)(in + off + 12);
    h8 u, v;
    u[0] = (f16)a.x; u[1] = (f16)a.y; u[2] = (f16)a.z; u[3] = (f16)a.w;
    u[4] = (f16)b.x; u[5] = (f16)b.y; u[6] = (f16)b.z; u[7] = (f16)b.w;
    v[0] = (f16)c.x; v[1] = (f16)c.y; v[2] = (f16)c.z; v[3] = (f16)c.w;
    v[4] = (f16)d.x; v[5] = (f16)d.y; v[6] = (f16)d.z; v[7] = (f16)d.w;
    *(h8*)(out + off) = u;
    *(h8*)(out + off + 8) = v;
  } else {
    __shared__ float t[32][33];
    const int bw = bx - 6400;
    const float* in = (bw >> 10) ? wk : wq;
    f16* out = (bw >> 10) ? okT : oqT;
    const int tile = bw & 1023;
    const int tr = tile >> 5, tc = tile & 31;
    {
      const int r = tid >> 3, c4 = (tid & 7) * 4;
      float4 v = *(const float4*)(in + (long)(tr * 32 + r) * 1024 + tc * 32 + c4);
      t[r][c4] = v.x; t[r][c4 + 1] = v.y; t[r][c4 + 2] = v.z; t[r][c4 + 3] = v.w;
    }
    __syncthreads();
    {
      const int rr = tid >> 3, cc4 = (tid & 7) * 4;
      h4 o;
      o[0] = (f16)t[cc4][rr]; o[1] = (f16)t[cc4 + 1][rr];
      o[2] = (f16)t[cc4 + 2][rr]; o[3] = (f16)t[cc4 + 3][rr];
      *(h4*)(out + (long)(tc * 32 + rr) * 1024 + tr * 32 + cc4) = o;
    }
  }
}

#define TILE 128
#define BK 32

// ---------- union dispatch: blocks [0,256) V^T projection (wide tile); [256,320) Mt ----------
__global__ __launch_bounds__(256, 2) void vt_mt(const f16* __restrict__ x3h,
                                                const f16* __restrict__ wvh,
                                                f16* __restrict__ vth,
                                                const f16* __restrict__ wkT,
                                                const f16* __restrict__ wqT,
                                                f16* __restrict__ mt) {
  __shared__ __align__(16) f16 smem[3 * 12288];  // 72 KiB (V^T branch); Mt uses 32 KiB

  const int tid = threadIdx.x;
  const int lane = tid & 63;
  const int w = tid >> 6;
  const int fr = lane & 15;
  const int g = lane >> 4;

  if (blockIdx.x < 256) {
    const int bx0 = blockIdx.x;
    const int wgid = (bx0 & 7) * 32 + (bx0 >> 3);  // bijective over 256
    const int by = wgid & 3;            // gy = 4
    const int bx = wgid >> 2;           // gx = 64
    const int m0 = bx * 128, n0 = by * 256;
    const int K = 1024, N = 1024;

    const int wm = w >> 1, wn = w & 1;
    const int r0 = tid >> 2;
    const int s = tid & 3;

    auto STAGE = [&](int sl, int t) {
      const long k0 = (long)t * 32;
#pragma unroll
      for (int c = 0; c < 2; ++c) {
        const int row = c * 64 + r0;
        const int scol = (s ^ ((row >> 1) & 3)) * 8;
        __builtin_amdgcn_global_load_lds(
            (gchar*)(x3h + (long)(m0 + row) * K + k0 + scol),
            (lchar*)(smem + sl * 12288 + c * 2048 + tid * 8), 16, 0, 0);
      }
#pragma unroll
      for (int c = 0; c < 4; ++c) {
        const int row = c * 64 + r0;
        const int scol = (s ^ ((row >> 1) & 3)) * 8;
        __builtin_amdgcn_global_load_lds(
            (gchar*)(wvh + (long)(n0 + row) * K + k0 + scol),
            (lchar*)(smem + sl * 12288 + 4096 + c * 2048 + tid * 8), 16, 0, 0);
      }
    };
    auto RDA = [&](int sl, int r) -> h8 {
      return *(const h8*)(smem + sl * 12288 + (r * 4 + (g ^ ((r >> 1) & 3))) * 8);
    };
    auto RDB = [&](int sl, int r) -> h8 {
      return *(const h8*)(smem + sl * 12288 + 4096 + (r * 4 + (g ^ ((r >> 1) & 3))) * 8);
    };

    f4 acc[4][8] = {};
    const int NT = K >> 5;

    STAGE(0, 0);
    STAGE(1, 1);
    vmwait<6>();
    __builtin_amdgcn_s_barrier();

    int sl = 0;
    for (int t = 0; t < NT; ++t) {
      h8 af[4], bf[8];
#pragma unroll
      for (int i = 0; i < 4; ++i) af[i] = RDA(sl, wm * 64 + i * 16 + fr);
#pragma unroll
      for (int j = 0; j < 8; ++j) bf[j] = RDB(sl, wn * 128 + j * 16 + fr);
      const int ts = (t + 2 < NT) ? t + 2 : NT - 1;
      int ss = sl + 2; if (ss >= 3) ss -= 3;
      STAGE(ss, ts);
      vmwait<6>();
      asm volatile("s_waitcnt lgkmcnt(0)" ::: "memory");
      __builtin_amdgcn_sched_barrier(0);
      __builtin_amdgcn_s_setprio(1);
#pragma unroll
      for (int mi = 0; mi < 4; ++mi)
#pragma unroll
        for (int ni = 0; ni < 8; ++ni)
          acc[mi][ni] = __builtin_amdgcn_mfma_f32_16x16x32_f16(af[mi], bf[ni], acc[mi][ni], 0, 0, 0);
      __builtin_amdgcn_s_setprio(0);
      __builtin_amdgcn_s_barrier();
      sl = (sl + 1 == 3) ? 0 : sl + 1;
    }
    vmwait<0>();

    const int fq = g * 4;
#pragma unroll
    for (int mi = 0; mi < 4; ++mi)
#pragma unroll
      for (int ni = 0; ni < 8; ++ni)
#pragma unroll
        for (int i = 0; i < 4; ++i) {
          const int row = m0 + wm * 64 + mi * 16 + fq + i;
          const int col = n0 + wn * 128 + ni * 16 + fr;
          const int b = row >> 11, sr = row & 2047;
          vth[((long)b * N + col) * 2048 + sr] = (f16)acc[mi][ni][i];
        }
  } else {
    // ---- Mt: 128x128 tile, 2-slot syncthreads loop ----
    const int bx2 = blockIdx.x - 256;
    const int m0 = (bx2 >> 3) * TILE;
    const int n0 = (bx2 & 7) * TILE;
    const int K = 1024, N = 1024;
    const int wr = w >> 1, wc = w & 1;

    const int lr = lane >> 2;
    const int lc = (lane & 3) * 8;
    const f16* Abase = wkT + (long)(m0 + lr) * K + lc;
    const f16* Bbase = wqT + (long)(n0 + lr) * K + lc;
    const int kg = g * 8;

    f4 acc[4][4] = {};

    auto STAGE2 = [&](int buf, int k0) {
#pragma unroll
      for (int c = 0; c < 2; ++c) {
        const int br = w * 32 + c * 16;
        __builtin_amdgcn_global_load_lds(
            (gchar*)(Abase + (long)br * K + k0),
            (lchar*)(smem + buf * 4096 + br * BK), 16, 0, 0);
        __builtin_amdgcn_global_load_lds(
            (gchar*)(Bbase + (long)br * K + k0),
            (lchar*)(smem + 8192 + buf * 4096 + br * BK), 16, 0, 0);
      }
    };

    STAGE2(0, 0);
    __syncthreads();

    int cur = 0;
    for (int k0 = 0; k0 < K; k0 += BK) {
      if (k0 + BK < K) STAGE2(cur ^ 1, k0 + BK);
      h8 af[4], bf[4];
#pragma unroll
      for (int i = 0; i < 4; ++i) {
        af[i] = *(const h8*)(smem + cur * 4096 + (wr * 64 + i * 16 + fr) * BK + kg);
        bf[i] = *(const h8*)(smem + 8192 + cur * 4096 + (wc * 64 + i * 16 + fr) * BK + kg);
      }
#pragma unroll
      for (int mi = 0; mi < 4; ++mi)
#pragma unroll
        for (int ni = 0; ni < 4; ++ni)
          acc[mi][ni] = __builtin_amdgcn_mfma_f32_16x16x32_f16(af[mi], bf[ni], acc[mi][ni], 0, 0, 0);
      __syncthreads();
      cur ^= 1;
    }

    const int fq = g * 4;
#pragma unroll
    for (int mi = 0; mi < 4; ++mi)
#pragma unroll
      for (int ni = 0; ni < 4; ++ni)
#pragma unroll
        for (int i = 0; i < 4; ++i) {
          const int row = m0 + wr * 64 + mi * 16 + fq + i;
          const int col = n0 + wc * 64 + ni * 16 + fr;
          mt[(long)row * N + col] = (f16)acc[mi][ni][i];
        }
  }
}

// ---------- WIDE GEMM: 128x256 tile, BK=32, 3-ring, counted vmcnt(6), T2 swizzle ----------
// MODE 1: f16 C = val * 0.03125 (Qeff projection, pre-scaled for scores)
// MODE 5: U = exp(val + mask) -> f16. Mask row-blocks 0,1 loaded BEFORE the prologue stages
//         (they retire at the prologue vmwait<6>, overlapping the whole K-loop); blocks 2,3
//         prefetched two-deep in the epilogue. All buffers named/static (no dyn indexing).
// MODE 6: f32 C = val / rowsum (PV; rowsum computed in-kernel from A=U)
template <int MODE>
__global__ __launch_bounds__(256, 2) void gemm128w(const f16* __restrict__ A,
                                                   const f16* __restrict__ Bm,
                                                   void* __restrict__ C,
                                                   const float* __restrict__ xtra,
                                                   int N, int K,
                                                   long sA, long sB, long sC,
                                                   int gx, int gy) {
  __shared__ __align__(16) f16 smem[3 * 12288];  // 72 KiB

  const int cpx = gridDim.x >> 3;
  const int wgid = (blockIdx.x & 7) * cpx + (blockIdx.x >> 3);
  const int by = wgid % gy;
  const int bx = (wgid / gy) % gx;
  const int bz = wgid / (gy * gx);
  A += (long)bz * sA;
  Bm += (long)bz * sB;
  const int m0 = bx * 128, n0 = by * 256;

  const int tid = threadIdx.x;
  const int lane = tid & 63;
  const int w = tid >> 6;
  const int wm = w >> 1, wn = w & 1;   // 2x2 waves; per-wave 64 rows x 128 cols
  const int fr = lane & 15;
  const int g = lane >> 4;

  const int r0 = tid >> 2;
  const int s = tid & 3;

  auto STAGE = [&](int sl, int t) {
    const long k0 = (long)t * 32;
#pragma unroll
    for (int c = 0; c < 2; ++c) {
      const int row = c * 64 + r0;
      const int scol = (s ^ ((row >> 1) & 3)) * 8;
      __builtin_amdgcn_global_load_lds(
          (gchar*)(A + (long)(m0 + row) * K + k0 + scol),
          (lchar*)(smem + sl * 12288 + c * 2048 + tid * 8), 16, 0, 0);
    }
#pragma unroll
    for (int c = 0; c < 4; ++c) {
      const int row = c * 64 + r0;
      const int scol = (s ^ ((row >> 1) & 3)) * 8;
      __builtin_amdgcn_global_load_lds(
          (gchar*)(Bm + (long)(n0 + row) * K + k0 + scol),
          (lchar*)(smem + sl * 12288 + 4096 + c * 2048 + tid * 8), 16, 0, 0);
    }
  };

  auto RDA = [&](int sl, int r) -> h8 {
    return *(const h8*)(smem + sl * 12288 + (r * 4 + (g ^ ((r >> 1) & 3))) * 8);
  };
  auto RDB = [&](int sl, int r) -> h8 {
    return *(const h8*)(smem + sl * 12288 + 4096 + (r * 4 + (g ^ ((r >> 1) & 3))) * 8);
  };

  const int fq = g * 4;
  f4 acc[4][8] = {};
  float pr[4] = {0.f, 0.f, 0.f, 0.f};  // MODE 6: per-A-frag-row partial sums of U
  float mA[32], mB[32];                // MODE 5: mask blocks 0,1 (issued pre-prologue)
  const float* mk = nullptr;
  const int NT = K >> 5;

  if constexpr (MODE == 5) {
    mk = xtra + (long)bz * sC;
#pragma unroll
    for (int ni = 0; ni < 8; ++ni)
#pragma unroll
      for (int i = 0; i < 4; ++i) {
        const int col = n0 + wn * 128 + ni * 16 + fr;
        mA[ni * 4 + i] = mk[(long)(m0 + wm * 64 + fq + i) * N + col];
        mB[ni * 4 + i] = mk[(long)(m0 + wm * 64 + 16 + fq + i) * N + col];
      }
    __builtin_amdgcn_sched_barrier(0);  // pin mask loads before stage DMA (oldest in vmcnt queue)
  }

  STAGE(0, 0);
  STAGE(1, 1);
  vmwait<6>();   // retires all mask loads + tile0; tile1's 6 stay in flight
  __builtin_amdgcn_s_barrier();

  int sl = 0;
  for (int t = 0; t < NT; ++t) {
    h8 af[4], bf[8];
#pragma unroll
    for (int i = 0; i < 4; ++i) af[i] = RDA(sl, wm * 64 + i * 16 + fr);
#pragma unroll
    for (int j = 0; j < 8; ++j) bf[j] = RDB(sl, wn * 128 + j * 16 + fr);
    if constexpr (MODE == 6) {
#pragma unroll
      for (int i = 0; i < 4; ++i) {
        f16 t0 = (f16)(((af[i][0] + af[i][1]) + (af[i][2] + af[i][3])) +
                       ((af[i][4] + af[i][5]) + (af[i][6] + af[i][7])));
        pr[i] += (float)t0;
      }
    }
    const int ts = (t + 2 < NT) ? t + 2 : NT - 1;
    int ss = sl + 2; if (ss >= 3) ss -= 3;
    STAGE(ss, ts);
    vmwait<6>();                   // tile t+1's 6 loads retired; t+2's in flight
    asm volatile("s_waitcnt lgkmcnt(0)" ::: "memory");
    __builtin_amdgcn_sched_barrier(0);
    __builtin_amdgcn_s_setprio(1);
#pragma unroll
    for (int mi = 0; mi < 4; ++mi)
#pragma unroll
      for (int ni = 0; ni < 8; ++ni)
        acc[mi][ni] = __builtin_amdgcn_mfma_f32_16x16x32_f16(af[mi], bf[ni], acc[mi][ni], 0, 0, 0);
    __builtin_amdgcn_s_setprio(0);
    __builtin_amdgcn_s_barrier();
    sl = (sl + 1 == 3) ? 0 : sl + 1;
  }
  vmwait<0>();

  if constexpr (MODE == 1) {
    f16* Cp = (f16*)C;
#pragma unroll
    for (int mi = 0; mi < 4; ++mi)
#pragma unroll
      for (int ni = 0; ni < 8; ++ni)
#pragma unroll
        for (int i = 0; i < 4; ++i) {
          const int row = m0 + wm * 64 + mi * 16 + fq + i;
          const int col = n0 + wn * 128 + ni * 16 + fr;
          Cp[(long)row * N + col] = (f16)(acc[mi][ni][i] * 0.03125f);
        }
  } else if constexpr (MODE == 5) {
    f16* Cp = (f16*)C + (long)bz * sC;
    float mC[32], mD[32];
    // block 0: prefetch block 2, compute from mA (preloaded)
#pragma unroll
    for (int ni = 0; ni < 8; ++ni)
#pragma unroll
      for (int i = 0; i < 4; ++i) {
        const int col = n0 + wn * 128 + ni * 16 + fr;
        mC[ni * 4 + i] = mk[(long)(m0 + wm * 64 + 32 + fq + i) * N + col];
      }
#pragma unroll
    for (int ni = 0; ni < 8; ++ni)
#pragma unroll
      for (int i = 0; i < 4; ++i) {
        const int row = m0 + wm * 64 + fq + i;
        const int col = n0 + wn * 128 + ni * 16 + fr;
        Cp[(long)row * N + col] = (f16)__expf(acc[0][ni][i] + mA[ni * 4 + i]);
      }
    // block 1: prefetch block 3, compute from mB (preloaded)
#pragma unroll
    for (int ni = 0; ni < 8; ++ni)
#pragma unroll
      for (int i = 0; i < 4; ++i) {
        const int col = n0 + wn * 128 + ni * 16 + fr;
        mD[ni * 4 + i] = mk[(long)(m0 + wm * 64 + 48 + fq + i) * N + col];
      }
#pragma unroll
    for (int ni = 0; ni < 8; ++ni)
#pragma unroll
      for (int i = 0; i < 4; ++i) {
        const int row = m0 + wm * 64 + 16 + fq + i;
        const int col = n0 + wn * 128 + ni * 16 + fr;
        Cp[(long)row * N + col] = (f16)__expf(acc[1][ni][i] + mB[ni * 4 + i]);
      }
    // blocks 2,3
#pragma unroll
    for (int ni = 0; ni < 8; ++ni)
#pragma unroll
      for (int i = 0; i < 4; ++i) {
        const int row = m0 + wm * 64 + 32 + fq + i;
        const int col = n0 + wn * 128 + ni * 16 + fr;
        Cp[(long)row * N + col] = (f16)__expf(acc[2][ni][i] + mC[ni * 4 + i]);
      }
#pragma unroll
    for (int ni = 0; ni < 8; ++ni)
#pragma unroll
      for (int i = 0; i < 4; ++i) {
        const int row = m0 + wm * 64 + 48 + fq + i;
        const int col = n0 + wn * 128 + ni * 16 + fr;
        Cp[(long)row * N + col] = (f16)__expf(acc[3][ni][i] + mD[ni * 4 + i]);
      }
  } else {
    // MODE 6: finish rowsums (reduce over g: xor 16,32; gather per-output-row) and divide.
    float* Cp = (float*)C + (long)bz * sC;
#pragma unroll
    for (int mi = 0; mi < 4; ++mi) {
      float sv = pr[mi];
      sv += __shfl_xor(sv, 16);
      sv += __shfl_xor(sv, 32);
#pragma unroll
      for (int i = 0; i < 4; ++i) {
        const float rsv = __shfl(sv, fq + i);
        const float inv = 1.0f / rsv;
        const int row = m0 + wm * 64 + mi * 16 + fq + i;
#pragma unroll
        for (int ni = 0; ni < 8; ++ni) {
          const int col = n0 + wn * 128 + ni * 16 + fr;
          Cp[(long)row * N + col] = acc[mi][ni][i] * inv;
        }
      }
    }
  }
}

extern "C" void kernel_launch(void* const* d_in, const int* in_sizes, int n_in,
                              void* d_out, int out_size, void* d_ws, size_t ws_size,
                              hipStream_t stream) {
  const float* x1 = (const float*)d_in[0];
  const float* x2 = (const float*)d_in[1];
  const float* x3 = (const float*)d_in[2];
  const float* mask = (const float*)d_in[3];
  const float* Wq = (const float*)d_in[4];
  const float* Wk = (const float*)d_in[5];
  const float* Wv = (const float*)d_in[6];

  const long nx = (long)B_ * S_ * D_;
  const long nw = (long)H_ * D_;
  const long nqkv = (long)B_ * S_ * H_;
  const long nsc = (long)B_ * S_ * S_;

  char* ws = (char*)d_ws;
  f16* x1h = (f16*)ws; ws += nx * 2;
  f16* x2h = (f16*)ws; ws += nx * 2;     // scores B-operand
  f16* x3h = (f16*)ws; ws += nx * 2;
  f16* wvh = (f16*)ws; ws += nw * 2;
  f16* wqT = (f16*)ws; ws += nw * 2;
  f16* wkT = (f16*)ws; ws += nw * 2;
  f16* mt  = (f16*)ws; ws += nw * 2;     // Mt[e][d] = sum_h Wk[h][e] Wq[h][d]
  f16* qh  = (f16*)ws; ws += nqkv * 2;   // Qeff = x1 * Mt^T * scale
  f16* vth = (f16*)ws; ws += nqkv * 2;   // V^T [b][h][s]
  f16* sc  = (f16*)ws; ws += nsc * 2;    // U = exp(scores + mask), f16

  prep<<<dim3(8448), 256, 0, stream>>>(x1, x2, x3, Wv, Wq, Wk,
                                       x1h, x2h, x3h, wvh, wqT, wkT);

  const dim3 blk(256);
  // union: V^T projection (256 blocks) + Mt (64 blocks)
  vt_mt<<<dim3(320), blk, 0, stream>>>(x3h, wvh, vth, wkT, wqT, mt);
  // Qeff = x1h * Mt^T * scale : wide tile, 64 x 4 = 256 blocks
  gemm128w<1><<<dim3(256), blk, 0, stream>>>(x1h, mt, qh, nullptr, 1024, 1024,
                                             0, 0, 0, 64, 4);
  // U[b] = exp(Qeff[b] x2[b]^T + mask[b]) -> f16 : 16 x 8 x 4 = 512 blocks
  gemm128w<5><<<dim3(512), blk, 0, stream>>>(qh, x2h, sc, mask, 2048, 1024,
                                             (long)S_ * H_, (long)S_ * D_, (long)S_ * S_, 16, 8);
  // out[b] = (U[b] (V^T[b])^T) / rowsum(U) : 16 x 4 x 4 = 256 blocks, rowsum in-kernel
  gemm128w<6><<<dim3(256), blk, 0, stream>>>(sc, vth, d_out, nullptr, 1024, 2048,
                                             (long)S_ * S_, (long)S_ * H_, (long)S_ * H_, 16, 4);
}

// Round 21
// 184.401 us; speedup vs baseline: 1.0301x; 1.0301x over previous
//
#include <hip/hip_runtime.h>

typedef _Float16 f16;
typedef _Float16 h4 __attribute__((ext_vector_type(4)));
typedef _Float16 h8 __attribute__((ext_vector_type(8)));
typedef float f4 __attribute__((ext_vector_type(4)));

typedef const __attribute__((address_space(1))) char gchar;
typedef __attribute__((address_space(3))) char lchar;

#define B_ 4
#define S_ 2048
#define D_ 1024
#define H_ 1024

template <int N>
__device__ __forceinline__ void vmwait() {
  if constexpr (N == 0) asm volatile("s_waitcnt vmcnt(0)" ::: "memory");
  else if constexpr (N == 6) asm volatile("s_waitcnt vmcnt(6)" ::: "memory");
}

// ---------------- prep: cast x1,x2,x3,Wv (16 elems/thread) + transpose-cast Wq,Wk ----------------
__global__ __launch_bounds__(256) void prep(
    const float* __restrict__ x1, const float* __restrict__ x2, const float* __restrict__ x3,
    const float* __restrict__ wv, const float* __restrict__ wq, const float* __restrict__ wk,
    f16* __restrict__ o1, f16* __restrict__ o2, f16* __restrict__ o3, f16* __restrict__ ow,
    f16* __restrict__ oqT, f16* __restrict__ okT) {
  const int bx = blockIdx.x;
  const int tid = threadIdx.x;
  if (bx < 6400) {
    const long g = bx * 256L + tid;
    const float* in;
    f16* out;
    long off;
    if (g < (3L << 19)) {
      const int w = (int)(g >> 19);
      off = (g & ((1L << 19) - 1)) * 16;
      in = w == 0 ? x1 : (w == 1 ? x2 : x3);
      out = w == 0 ? o1 : (w == 1 ? o2 : o3);
    } else {
      off = (g - (3L << 19)) * 16;
      in = wv;
      out = ow;
    }
    float4 a = *(const float4*)(in + off);
    float4 b = *(const float4*)(in + off + 4);
    float4 c = *(const float4*)(in + off + 8);
    float4 d = *(const float4*)(in + off + 12);
    h8 u, v;
    u[0] = (f16)a.x; u[1] = (f16)a.y; u[2] = (f16)a.z; u[3] = (f16)a.w;
    u[4] = (f16)b.x; u[5] = (f16)b.y; u[6] = (f16)b.z; u[7] = (f16)b.w;
    v[0] = (f16)c.x; v[1] = (f16)c.y; v[2] = (f16)c.z; v[3] = (f16)c.w;
    v[4] = (f16)d.x; v[5] = (f16)d.y; v[6] = (f16)d.z; v[7] = (f16)d.w;
    *(h8*)(out + off) = u;
    *(h8*)(out + off + 8) = v;
  } else {
    __shared__ float t[32][33];
    const int bw = bx - 6400;
    const float* in = (bw >> 10) ? wk : wq;
    f16* out = (bw >> 10) ? okT : oqT;
    const int tile = bw & 1023;
    const int tr = tile >> 5, tc = tile & 31;
    {
      const int r = tid >> 3, c4 = (tid & 7) * 4;
      float4 v = *(const float4*)(in + (long)(tr * 32 + r) * 1024 + tc * 32 + c4);
      t[r][c4] = v.x; t[r][c4 + 1] = v.y; t[r][c4 + 2] = v.z; t[r][c4 + 3] = v.w;
    }
    __syncthreads();
    {
      const int rr = tid >> 3, cc4 = (tid & 7) * 4;
      h4 o;
      o[0] = (f16)t[cc4][rr]; o[1] = (f16)t[cc4 + 1][rr];
      o[2] = (f16)t[cc4 + 2][rr]; o[3] = (f16)t[cc4 + 3][rr];
      *(h4*)(out + (long)(tc * 32 + rr) * 1024 + tr * 32 + cc4) = o;
    }
  }
}

#define TILE 128
#define BK 32

// ---------- union dispatch: blocks [0,256) V^T projection (wide tile); [256,320) Mt ----------
__global__ __launch_bounds__(256, 2) void vt_mt(const f16* __restrict__ x3h,
                                                const f16* __restrict__ wvh,
                                                f16* __restrict__ vth,
                                                const f16* __restrict__ wkT,
                                                const f16* __restrict__ wqT,
                                                f16* __restrict__ mt) {
  __shared__ __align__(16) f16 smem[3 * 12288];  // 72 KiB (V^T branch); Mt uses 32 KiB

  const int tid = threadIdx.x;
  const int lane = tid & 63;
  const int w = tid >> 6;
  const int fr = lane & 15;
  const int g = lane >> 4;

  if (blockIdx.x < 256) {
    const int bx0 = blockIdx.x;
    const int wgid = (bx0 & 7) * 32 + (bx0 >> 3);  // bijective over 256
    const int by = wgid & 3;            // gy = 4
    const int bx = wgid >> 2;           // gx = 64
    const int m0 = bx * 128, n0 = by * 256;
    const int K = 1024, N = 1024;

    const int wm = w >> 1, wn = w & 1;
    const int r0 = tid >> 2;
    const int s = tid & 3;

    auto STAGE = [&](int sl, int t) {
      const long k0 = (long)t * 32;
#pragma unroll
      for (int c = 0; c < 2; ++c) {
        const int row = c * 64 + r0;
        const int scol = (s ^ ((row >> 1) & 3)) * 8;
        __builtin_amdgcn_global_load_lds(
            (gchar*)(x3h + (long)(m0 + row) * K + k0 + scol),
            (lchar*)(smem + sl * 12288 + c * 2048 + tid * 8), 16, 0, 0);
      }
#pragma unroll
      for (int c = 0; c < 4; ++c) {
        const int row = c * 64 + r0;
        const int scol = (s ^ ((row >> 1) & 3)) * 8;
        __builtin_amdgcn_global_load_lds(
            (gchar*)(wvh + (long)(n0 + row) * K + k0 + scol),
            (lchar*)(smem + sl * 12288 + 4096 + c * 2048 + tid * 8), 16, 0, 0);
      }
    };
    auto RDA = [&](int sl, int r) -> h8 {
      return *(const h8*)(smem + sl * 12288 + (r * 4 + (g ^ ((r >> 1) & 3))) * 8);
    };
    auto RDB = [&](int sl, int r) -> h8 {
      return *(const h8*)(smem + sl * 12288 + 4096 + (r * 4 + (g ^ ((r >> 1) & 3))) * 8);
    };

    f4 acc[4][8] = {};
    const int NT = K >> 5;

    STAGE(0, 0);
    STAGE(1, 1);
    vmwait<6>();
    __builtin_amdgcn_s_barrier();

    int sl = 0;
    for (int t = 0; t < NT; ++t) {
      h8 af[4], bf[8];
#pragma unroll
      for (int i = 0; i < 4; ++i) af[i] = RDA(sl, wm * 64 + i * 16 + fr);
#pragma unroll
      for (int j = 0; j < 8; ++j) bf[j] = RDB(sl, wn * 128 + j * 16 + fr);
      const int ts = (t + 2 < NT) ? t + 2 : NT - 1;
      int ss = sl + 2; if (ss >= 3) ss -= 3;
      STAGE(ss, ts);
      vmwait<6>();
      asm volatile("s_waitcnt lgkmcnt(0)" ::: "memory");
      __builtin_amdgcn_sched_barrier(0);
      __builtin_amdgcn_s_setprio(1);
#pragma unroll
      for (int mi = 0; mi < 4; ++mi)
#pragma unroll
        for (int ni = 0; ni < 8; ++ni)
          acc[mi][ni] = __builtin_amdgcn_mfma_f32_16x16x32_f16(af[mi], bf[ni], acc[mi][ni], 0, 0, 0);
      __builtin_amdgcn_s_setprio(0);
      __builtin_amdgcn_s_barrier();
      sl = (sl + 1 == 3) ? 0 : sl + 1;
    }
    vmwait<0>();

    const int fq = g * 4;
#pragma unroll
    for (int mi = 0; mi < 4; ++mi)
#pragma unroll
      for (int ni = 0; ni < 8; ++ni)
#pragma unroll
        for (int i = 0; i < 4; ++i) {
          const int row = m0 + wm * 64 + mi * 16 + fq + i;
          const int col = n0 + wn * 128 + ni * 16 + fr;
          const int b = row >> 11, sr = row & 2047;
          vth[((long)b * N + col) * 2048 + sr] = (f16)acc[mi][ni][i];
        }
  } else {
    // ---- Mt: 128x128 tile, 2-slot syncthreads loop ----
    const int bx2 = blockIdx.x - 256;
    const int m0 = (bx2 >> 3) * TILE;
    const int n0 = (bx2 & 7) * TILE;
    const int K = 1024, N = 1024;
    const int wr = w >> 1, wc = w & 1;

    const int lr = lane >> 2;
    const int lc = (lane & 3) * 8;
    const f16* Abase = wkT + (long)(m0 + lr) * K + lc;
    const f16* Bbase = wqT + (long)(n0 + lr) * K + lc;
    const int kg = g * 8;

    f4 acc[4][4] = {};

    auto STAGE2 = [&](int buf, int k0) {
#pragma unroll
      for (int c = 0; c < 2; ++c) {
        const int br = w * 32 + c * 16;
        __builtin_amdgcn_global_load_lds(
            (gchar*)(Abase + (long)br * K + k0),
            (lchar*)(smem + buf * 4096 + br * BK), 16, 0, 0);
        __builtin_amdgcn_global_load_lds(
            (gchar*)(Bbase + (long)br * K + k0),
            (lchar*)(smem + 8192 + buf * 4096 + br * BK), 16, 0, 0);
      }
    };

    STAGE2(0, 0);
    __syncthreads();

    int cur = 0;
    for (int k0 = 0; k0 < K; k0 += BK) {
      if (k0 + BK < K) STAGE2(cur ^ 1, k0 + BK);
      h8 af[4], bf[4];
#pragma unroll
      for (int i = 0; i < 4; ++i) {
        af[i] = *(const h8*)(smem + cur * 4096 + (wr * 64 + i * 16 + fr) * BK + kg);
        bf[i] = *(const h8*)(smem + 8192 + cur * 4096 + (wc * 64 + i * 16 + fr) * BK + kg);
      }
#pragma unroll
      for (int mi = 0; mi < 4; ++mi)
#pragma unroll
        for (int ni = 0; ni < 4; ++ni)
          acc[mi][ni] = __builtin_amdgcn_mfma_f32_16x16x32_f16(af[mi], bf[ni], acc[mi][ni], 0, 0, 0);
      __syncthreads();
      cur ^= 1;
    }

    const int fq = g * 4;
#pragma unroll
    for (int mi = 0; mi < 4; ++mi)
#pragma unroll
      for (int ni = 0; ni < 4; ++ni)
#pragma unroll
        for (int i = 0; i < 4; ++i) {
          const int row = m0 + wr * 64 + mi * 16 + fq + i;
          const int col = n0 + wc * 64 + ni * 16 + fr;
          mt[(long)row * N + col] = (f16)acc[mi][ni][i];
        }
  }
}

// ---------- WIDE GEMM: 128x256 tile, BK=32, 3-ring, counted vmcnt(6), T2 swizzle ----------
// MODE 1: f16 C = val * 0.03125 (Qeff projection, pre-scaled for scores)
// MODE 5: U = exp(val + mask) -> f16 (scores; mask loads double-buffered over mi-blocks)
// MODE 6: f32 C = val / rowsum (PV; rowsum computed in-kernel from A=U)
template <int MODE>
__global__ __launch_bounds__(256, 2) void gemm128w(const f16* __restrict__ A,
                                                   const f16* __restrict__ Bm,
                                                   void* __restrict__ C,
                                                   const float* __restrict__ xtra,
                                                   int N, int K,
                                                   long sA, long sB, long sC,
                                                   int gx, int gy) {
  __shared__ __align__(16) f16 smem[3 * 12288];  // 72 KiB

  const int cpx = gridDim.x >> 3;
  const int wgid = (blockIdx.x & 7) * cpx + (blockIdx.x >> 3);
  const int by = wgid % gy;
  const int bx = (wgid / gy) % gx;
  const int bz = wgid / (gy * gx);
  A += (long)bz * sA;
  Bm += (long)bz * sB;
  const int m0 = bx * 128, n0 = by * 256;

  const int tid = threadIdx.x;
  const int lane = tid & 63;
  const int w = tid >> 6;
  const int wm = w >> 1, wn = w & 1;   // 2x2 waves; per-wave 64 rows x 128 cols
  const int fr = lane & 15;
  const int g = lane >> 4;

  const int r0 = tid >> 2;
  const int s = tid & 3;

  auto STAGE = [&](int sl, int t) {
    const long k0 = (long)t * 32;
#pragma unroll
    for (int c = 0; c < 2; ++c) {
      const int row = c * 64 + r0;
      const int scol = (s ^ ((row >> 1) & 3)) * 8;
      __builtin_amdgcn_global_load_lds(
          (gchar*)(A + (long)(m0 + row) * K + k0 + scol),
          (lchar*)(smem + sl * 12288 + c * 2048 + tid * 8), 16, 0, 0);
    }
#pragma unroll
    for (int c = 0; c < 4; ++c) {
      const int row = c * 64 + r0;
      const int scol = (s ^ ((row >> 1) & 3)) * 8;
      __builtin_amdgcn_global_load_lds(
          (gchar*)(Bm + (long)(n0 + row) * K + k0 + scol),
          (lchar*)(smem + sl * 12288 + 4096 + c * 2048 + tid * 8), 16, 0, 0);
    }
  };

  auto RDA = [&](int sl, int r) -> h8 {
    return *(const h8*)(smem + sl * 12288 + (r * 4 + (g ^ ((r >> 1) & 3))) * 8);
  };
  auto RDB = [&](int sl, int r) -> h8 {
    return *(const h8*)(smem + sl * 12288 + 4096 + (r * 4 + (g ^ ((r >> 1) & 3))) * 8);
  };

  f4 acc[4][8] = {};
  float pr[4] = {0.f, 0.f, 0.f, 0.f};  // MODE 6: per-A-frag-row partial sums of U
  const int NT = K >> 5;

  STAGE(0, 0);
  STAGE(1, 1);
  vmwait<6>();
  __builtin_amdgcn_s_barrier();

  int sl = 0;
  for (int t = 0; t < NT; ++t) {
    h8 af[4], bf[8];
#pragma unroll
    for (int i = 0; i < 4; ++i) af[i] = RDA(sl, wm * 64 + i * 16 + fr);
#pragma unroll
    for (int j = 0; j < 8; ++j) bf[j] = RDB(sl, wn * 128 + j * 16 + fr);
    if constexpr (MODE == 6) {
#pragma unroll
      for (int i = 0; i < 4; ++i) {
        f16 t0 = (f16)(((af[i][0] + af[i][1]) + (af[i][2] + af[i][3])) +
                       ((af[i][4] + af[i][5]) + (af[i][6] + af[i][7])));
        pr[i] += (float)t0;
      }
    }
    const int ts = (t + 2 < NT) ? t + 2 : NT - 1;
    int ss = sl + 2; if (ss >= 3) ss -= 3;
    STAGE(ss, ts);
    vmwait<6>();                   // tile t+1's 6 loads retired; t+2's in flight
    asm volatile("s_waitcnt lgkmcnt(0)" ::: "memory");
    __builtin_amdgcn_sched_barrier(0);
    __builtin_amdgcn_s_setprio(1);
#pragma unroll
    for (int mi = 0; mi < 4; ++mi)
#pragma unroll
      for (int ni = 0; ni < 8; ++ni)
        acc[mi][ni] = __builtin_amdgcn_mfma_f32_16x16x32_f16(af[mi], bf[ni], acc[mi][ni], 0, 0, 0);
    __builtin_amdgcn_s_setprio(0);
    __builtin_amdgcn_s_barrier();
    sl = (sl + 1 == 3) ? 0 : sl + 1;
  }
  vmwait<0>();

  const int fq = g * 4;
  if constexpr (MODE == 1) {
    f16* Cp = (f16*)C;
#pragma unroll
    for (int mi = 0; mi < 4; ++mi)
#pragma unroll
      for (int ni = 0; ni < 8; ++ni)
#pragma unroll
        for (int i = 0; i < 4; ++i) {
          const int row = m0 + wm * 64 + mi * 16 + fq + i;
          const int col = n0 + wn * 128 + ni * 16 + fr;
          Cp[(long)row * N + col] = (f16)(acc[mi][ni][i] * 0.03125f);
        }
  } else if constexpr (MODE == 5) {
    // pipelined mask prefetch: load mi+1's 32 mask values while exp/storing mi
    const float* mk = xtra + (long)bz * sC;
    f16* Cp = (f16*)C + (long)bz * sC;
    float mb0[32], mb1[32];
#pragma unroll
    for (int ni = 0; ni < 8; ++ni)
#pragma unroll
      for (int i = 0; i < 4; ++i) {
        const int row = m0 + wm * 64 + fq + i;
        const int col = n0 + wn * 128 + ni * 16 + fr;
        mb0[ni * 4 + i] = mk[(long)row * N + col];
      }
#pragma unroll
    for (int mi = 0; mi < 4; ++mi) {
      float* curb = (mi & 1) ? mb1 : mb0;
      float* nxtb = (mi & 1) ? mb0 : mb1;
      if (mi < 3) {
#pragma unroll
        for (int ni = 0; ni < 8; ++ni)
#pragma unroll
          for (int i = 0; i < 4; ++i) {
            const int row = m0 + wm * 64 + (mi + 1) * 16 + fq + i;
            const int col = n0 + wn * 128 + ni * 16 + fr;
            nxtb[ni * 4 + i] = mk[(long)row * N + col];
          }
      }
#pragma unroll
      for (int ni = 0; ni < 8; ++ni)
#pragma unroll
        for (int i = 0; i < 4; ++i) {
          const int row = m0 + wm * 64 + mi * 16 + fq + i;
          const int col = n0 + wn * 128 + ni * 16 + fr;
          Cp[(long)row * N + col] = (f16)__expf(acc[mi][ni][i] + curb[ni * 4 + i]);
        }
    }
  } else {
    // MODE 6: finish rowsums (reduce over g: xor 16,32; gather per-output-row) and divide.
    float* Cp = (float*)C + (long)bz * sC;
#pragma unroll
    for (int mi = 0; mi < 4; ++mi) {
      float sv = pr[mi];
      sv += __shfl_xor(sv, 16);
      sv += __shfl_xor(sv, 32);
#pragma unroll
      for (int i = 0; i < 4; ++i) {
        const float rsv = __shfl(sv, fq + i);
        const float inv = 1.0f / rsv;
        const int row = m0 + wm * 64 + mi * 16 + fq + i;
#pragma unroll
        for (int ni = 0; ni < 8; ++ni) {
          const int col = n0 + wn * 128 + ni * 16 + fr;
          Cp[(long)row * N + col] = acc[mi][ni][i] * inv;
        }
      }
    }
  }
}

extern "C" void kernel_launch(void* const* d_in, const int* in_sizes, int n_in,
                              void* d_out, int out_size, void* d_ws, size_t ws_size,
                              hipStream_t stream) {
  const float* x1 = (const float*)d_in[0];
  const float* x2 = (const float*)d_in[1];
  const float* x3 = (const float*)d_in[2];
  const float* mask = (const float*)d_in[3];
  const float* Wq = (const float*)d_in[4];
  const float* Wk = (const float*)d_in[5];
  const float* Wv = (const float*)d_in[6];

  const long nx = (long)B_ * S_ * D_;
  const long nw = (long)H_ * D_;
  const long nqkv = (long)B_ * S_ * H_;
  const long nsc = (long)B_ * S_ * S_;

  char* ws = (char*)d_ws;
  f16* x1h = (f16*)ws; ws += nx * 2;
  f16* x2h = (f16*)ws; ws += nx * 2;     // scores B-operand
  f16* x3h = (f16*)ws; ws += nx * 2;
  f16* wvh = (f16*)ws; ws += nw * 2;
  f16* wqT = (f16*)ws; ws += nw * 2;
  f16* wkT = (f16*)ws; ws += nw * 2;
  f16* mt  = (f16*)ws; ws += nw * 2;     // Mt[e][d] = sum_h Wk[h][e] Wq[h][d]
  f16* qh  = (f16*)ws; ws += nqkv * 2;   // Qeff = x1 * Mt^T * scale
  f16* vth = (f16*)ws; ws += nqkv * 2;   // V^T [b][h][s]
  f16* sc  = (f16*)ws; ws += nsc * 2;    // U = exp(scores + mask), f16

  prep<<<dim3(8448), 256, 0, stream>>>(x1, x2, x3, Wv, Wq, Wk,
                                       x1h, x2h, x3h, wvh, wqT, wkT);

  const dim3 blk(256);
  // union: V^T projection (256 blocks) + Mt (64 blocks)
  vt_mt<<<dim3(320), blk, 0, stream>>>(x3h, wvh, vth, wkT, wqT, mt);
  // Qeff = x1h * Mt^T * scale : wide tile, 64 x 4 = 256 blocks
  gemm128w<1><<<dim3(256), blk, 0, stream>>>(x1h, mt, qh, nullptr, 1024, 1024,
                                             0, 0, 0, 64, 4);
  // U[b] = exp(Qeff[b] x2[b]^T + mask[b]) -> f16 : 16 x 8 x 4 = 512 blocks
  gemm128w<5><<<dim3(512), blk, 0, stream>>>(qh, x2h, sc, mask, 2048, 1024,
                                             (long)S_ * H_, (long)S_ * D_, (long)S_ * S_, 16, 8);
  // out[b] = (U[b] (V^T[b])^T) / rowsum(U) : 16 x 4 x 4 = 256 blocks, rowsum in-kernel
  gemm128w<6><<<dim3(256), blk, 0, stream>>>(sc, vth, d_out, nullptr, 1024, 2048,
                                             (long)S_ * S_, (long)S_ * H_, (long)S_ * H_, 16, 4);
}

// Round 22
// 183.418 us; speedup vs baseline: 1.0356x; 1.0054x over previous
//
#include <hip/hip_runtime.h>

typedef _Float16 f16;
typedef _Float16 h4 __attribute__((ext_vector_type(4)));
typedef _Float16 h8 __attribute__((ext_vector_type(8)));
typedef float f4 __attribute__((ext_vector_type(4)));

typedef const __attribute__((address_space(1))) char gchar;
typedef __attribute__((address_space(3))) char lchar;

#define B_ 4
#define S_ 2048
#define D_ 1024
#define H_ 1024

template <int N>
__device__ __forceinline__ void vmwait() {
  if constexpr (N == 0) asm volatile("s_waitcnt vmcnt(0)" ::: "memory");
  else if constexpr (N == 6) asm volatile("s_waitcnt vmcnt(6)" ::: "memory");
  else if constexpr (N == 8) asm volatile("s_waitcnt vmcnt(8)" ::: "memory");
}

// ---------------- prep: cast x1,x2,x3,Wv (16 elems/thread) + transpose-cast Wq,Wk ----------------
__global__ __launch_bounds__(256) void prep(
    const float* __restrict__ x1, const float* __restrict__ x2, const float* __restrict__ x3,
    const float* __restrict__ wv, const float* __restrict__ wq, const float* __restrict__ wk,
    f16* __restrict__ o1, f16* __restrict__ o2, f16* __restrict__ o3, f16* __restrict__ ow,
    f16* __restrict__ oqT, f16* __restrict__ okT) {
  const int bx = blockIdx.x;
  const int tid = threadIdx.x;
  if (bx < 6400) {
    const long g = bx * 256L + tid;
    const float* in;
    f16* out;
    long off;
    if (g < (3L << 19)) {
      const int w = (int)(g >> 19);
      off = (g & ((1L << 19) - 1)) * 16;
      in = w == 0 ? x1 : (w == 1 ? x2 : x3);
      out = w == 0 ? o1 : (w == 1 ? o2 : o3);
    } else {
      off = (g - (3L << 19)) * 16;
      in = wv;
      out = ow;
    }
    float4 a = *(const float4*)(in + off);
    float4 b = *(const float4*)(in + off + 4);
    float4 c = *(const float4*)(in + off + 8);
    float4 d = *(const float4*)(in + off + 12);
    h8 u, v;
    u[0] = (f16)a.x; u[1] = (f16)a.y; u[2] = (f16)a.z; u[3] = (f16)a.w;
    u[4] = (f16)b.x; u[5] = (f16)b.y; u[6] = (f16)b.z; u[7] = (f16)b.w;
    v[0] = (f16)c.x; v[1] = (f16)c.y; v[2] = (f16)c.z; v[3] = (f16)c.w;
    v[4] = (f16)d.x; v[5] = (f16)d.y; v[6] = (f16)d.z; v[7] = (f16)d.w;
    *(h8*)(out + off) = u;
    *(h8*)(out + off + 8) = v;
  } else {
    __shared__ float t[32][33];
    const int bw = bx - 6400;
    const float* in = (bw >> 10) ? wk : wq;
    f16* out = (bw >> 10) ? okT : oqT;
    const int tile = bw & 1023;
    const int tr = tile >> 5, tc = tile & 31;
    {
      const int r = tid >> 3, c4 = (tid & 7) * 4;
      float4 v = *(const float4*)(in + (long)(tr * 32 + r) * 1024 + tc * 32 + c4);
      t[r][c4] = v.x; t[r][c4 + 1] = v.y; t[r][c4 + 2] = v.z; t[r][c4 + 3] = v.w;
    }
    __syncthreads();
    {
      const int rr = tid >> 3, cc4 = (tid & 7) * 4;
      h4 o;
      o[0] = (f16)t[cc4][rr]; o[1] = (f16)t[cc4 + 1][rr];
      o[2] = (f16)t[cc4 + 2][rr]; o[3] = (f16)t[cc4 + 3][rr];
      *(h4*)(out + (long)(tc * 32 + rr) * 1024 + tr * 32 + cc4) = o;
    }
  }
}

#define TILE 128
#define BK 32

// ---------- union dispatch: blocks [0,256) V^T projection (wide tile); [256,320) Mt ----------
__global__ __launch_bounds__(256, 2) void vt_mt(const f16* __restrict__ x3h,
                                                const f16* __restrict__ wvh,
                                                f16* __restrict__ vth,
                                                const f16* __restrict__ wkT,
                                                const f16* __restrict__ wqT,
                                                f16* __restrict__ mt) {
  __shared__ __align__(16) f16 smem[3 * 12288];  // 72 KiB (V^T branch); Mt uses 32 KiB

  const int tid = threadIdx.x;
  const int lane = tid & 63;
  const int w = tid >> 6;
  const int fr = lane & 15;
  const int g = lane >> 4;

  if (blockIdx.x < 256) {
    const int bx0 = blockIdx.x;
    const int wgid = (bx0 & 7) * 32 + (bx0 >> 3);  // bijective over 256
    const int by = wgid & 3;            // gy = 4
    const int bx = wgid >> 2;           // gx = 64
    const int m0 = bx * 128, n0 = by * 256;
    const int K = 1024, N = 1024;

    const int wm = w >> 1, wn = w & 1;
    const int r0 = tid >> 2;
    const int s = tid & 3;

    auto STAGE = [&](int sl, int t) {
      const long k0 = (long)t * 32;
#pragma unroll
      for (int c = 0; c < 2; ++c) {
        const int row = c * 64 + r0;
        const int scol = (s ^ ((row >> 1) & 3)) * 8;
        __builtin_amdgcn_global_load_lds(
            (gchar*)(x3h + (long)(m0 + row) * K + k0 + scol),
            (lchar*)(smem + sl * 12288 + c * 2048 + tid * 8), 16, 0, 0);
      }
#pragma unroll
      for (int c = 0; c < 4; ++c) {
        const int row = c * 64 + r0;
        const int scol = (s ^ ((row >> 1) & 3)) * 8;
        __builtin_amdgcn_global_load_lds(
            (gchar*)(wvh + (long)(n0 + row) * K + k0 + scol),
            (lchar*)(smem + sl * 12288 + 4096 + c * 2048 + tid * 8), 16, 0, 0);
      }
    };
    auto RDA = [&](int sl, int r) -> h8 {
      return *(const h8*)(smem + sl * 12288 + (r * 4 + (g ^ ((r >> 1) & 3))) * 8);
    };
    auto RDB = [&](int sl, int r) -> h8 {
      return *(const h8*)(smem + sl * 12288 + 4096 + (r * 4 + (g ^ ((r >> 1) & 3))) * 8);
    };

    f4 acc[4][8] = {};
    const int NT = K >> 5;

    STAGE(0, 0);
    STAGE(1, 1);
    vmwait<6>();
    __builtin_amdgcn_s_barrier();

    int sl = 0;
    for (int t = 0; t < NT; ++t) {
      h8 af[4], bf[8];
#pragma unroll
      for (int i = 0; i < 4; ++i) af[i] = RDA(sl, wm * 64 + i * 16 + fr);
#pragma unroll
      for (int j = 0; j < 8; ++j) bf[j] = RDB(sl, wn * 128 + j * 16 + fr);
      const int ts = (t + 2 < NT) ? t + 2 : NT - 1;
      int ss = sl + 2; if (ss >= 3) ss -= 3;
      STAGE(ss, ts);
      vmwait<6>();
      asm volatile("s_waitcnt lgkmcnt(0)" ::: "memory");
      __builtin_amdgcn_sched_barrier(0);
      __builtin_amdgcn_s_setprio(1);
#pragma unroll
      for (int mi = 0; mi < 4; ++mi)
#pragma unroll
        for (int ni = 0; ni < 8; ++ni)
          acc[mi][ni] = __builtin_amdgcn_mfma_f32_16x16x32_f16(af[mi], bf[ni], acc[mi][ni], 0, 0, 0);
      __builtin_amdgcn_s_setprio(0);
      __builtin_amdgcn_s_barrier();
      sl = (sl + 1 == 3) ? 0 : sl + 1;
    }
    vmwait<0>();

    const int fq = g * 4;
#pragma unroll
    for (int mi = 0; mi < 4; ++mi)
#pragma unroll
      for (int ni = 0; ni < 8; ++ni)
#pragma unroll
        for (int i = 0; i < 4; ++i) {
          const int row = m0 + wm * 64 + mi * 16 + fq + i;
          const int col = n0 + wn * 128 + ni * 16 + fr;
          const int b = row >> 11, sr = row & 2047;
          vth[((long)b * N + col) * 2048 + sr] = (f16)acc[mi][ni][i];
        }
  } else {
    // ---- Mt: 128x128 tile, 2-slot syncthreads loop ----
    const int bx2 = blockIdx.x - 256;
    const int m0 = (bx2 >> 3) * TILE;
    const int n0 = (bx2 & 7) * TILE;
    const int K = 1024, N = 1024;
    const int wr = w >> 1, wc = w & 1;

    const int lr = lane >> 2;
    const int lc = (lane & 3) * 8;
    const f16* Abase = wkT + (long)(m0 + lr) * K + lc;
    const f16* Bbase = wqT + (long)(n0 + lr) * K + lc;
    const int kg = g * 8;

    f4 acc[4][4] = {};

    auto STAGE2 = [&](int buf, int k0) {
#pragma unroll
      for (int c = 0; c < 2; ++c) {
        const int br = w * 32 + c * 16;
        __builtin_amdgcn_global_load_lds(
            (gchar*)(Abase + (long)br * K + k0),
            (lchar*)(smem + buf * 4096 + br * BK), 16, 0, 0);
        __builtin_amdgcn_global_load_lds(
            (gchar*)(Bbase + (long)br * K + k0),
            (lchar*)(smem + 8192 + buf * 4096 + br * BK), 16, 0, 0);
      }
    };

    STAGE2(0, 0);
    __syncthreads();

    int cur = 0;
    for (int k0 = 0; k0 < K; k0 += BK) {
      if (k0 + BK < K) STAGE2(cur ^ 1, k0 + BK);
      h8 af[4], bf[4];
#pragma unroll
      for (int i = 0; i < 4; ++i) {
        af[i] = *(const h8*)(smem + cur * 4096 + (wr * 64 + i * 16 + fr) * BK + kg);
        bf[i] = *(const h8*)(smem + 8192 + cur * 4096 + (wc * 64 + i * 16 + fr) * BK + kg);
      }
#pragma unroll
      for (int mi = 0; mi < 4; ++mi)
#pragma unroll
        for (int ni = 0; ni < 4; ++ni)
          acc[mi][ni] = __builtin_amdgcn_mfma_f32_16x16x32_f16(af[mi], bf[ni], acc[mi][ni], 0, 0, 0);
      __syncthreads();
      cur ^= 1;
    }

    const int fq = g * 4;
#pragma unroll
    for (int mi = 0; mi < 4; ++mi)
#pragma unroll
      for (int ni = 0; ni < 4; ++ni)
#pragma unroll
        for (int i = 0; i < 4; ++i) {
          const int row = m0 + wr * 64 + mi * 16 + fq + i;
          const int col = n0 + wc * 64 + ni * 16 + fr;
          mt[(long)row * N + col] = (f16)acc[mi][ni][i];
        }
  }
}

// ---------- WIDE GEMM: 128x256 tile, BK=32, 3-ring, counted vmcnt(6), T2 swizzle ----------
// MODE 1: f16 C = val * 0.03125 (Qeff projection, pre-scaled for scores)
// MODE 5: U = exp(val + mask) -> f16; mask staged through dead post-loop LDS via
//         global_load_lds (4 chunks x 32 rows, 2-buffer pipeline, counted vmcnt)
// MODE 6: f32 C = val / rowsum (PV; rowsum computed in-kernel from A=U)
template <int MODE>
__global__ __launch_bounds__(256, 2) void gemm128w(const f16* __restrict__ A,
                                                   const f16* __restrict__ Bm,
                                                   void* __restrict__ C,
                                                   const float* __restrict__ xtra,
                                                   int N, int K,
                                                   long sA, long sB, long sC,
                                                   int gx, int gy) {
  __shared__ __align__(16) f16 smem[3 * 12288];  // 72 KiB

  const int cpx = gridDim.x >> 3;
  const int wgid = (blockIdx.x & 7) * cpx + (blockIdx.x >> 3);
  const int by = wgid % gy;
  const int bx = (wgid / gy) % gx;
  const int bz = wgid / (gy * gx);
  A += (long)bz * sA;
  Bm += (long)bz * sB;
  const int m0 = bx * 128, n0 = by * 256;

  const int tid = threadIdx.x;
  const int lane = tid & 63;
  const int w = tid >> 6;
  const int wm = w >> 1, wn = w & 1;   // 2x2 waves; per-wave 64 rows x 128 cols
  const int fr = lane & 15;
  const int g = lane >> 4;

  const int r0 = tid >> 2;
  const int s = tid & 3;

  auto STAGE = [&](int sl, int t) {
    const long k0 = (long)t * 32;
#pragma unroll
    for (int c = 0; c < 2; ++c) {
      const int row = c * 64 + r0;
      const int scol = (s ^ ((row >> 1) & 3)) * 8;
      __builtin_amdgcn_global_load_lds(
          (gchar*)(A + (long)(m0 + row) * K + k0 + scol),
          (lchar*)(smem + sl * 12288 + c * 2048 + tid * 8), 16, 0, 0);
    }
#pragma unroll
    for (int c = 0; c < 4; ++c) {
      const int row = c * 64 + r0;
      const int scol = (s ^ ((row >> 1) & 3)) * 8;
      __builtin_amdgcn_global_load_lds(
          (gchar*)(Bm + (long)(n0 + row) * K + k0 + scol),
          (lchar*)(smem + sl * 12288 + 4096 + c * 2048 + tid * 8), 16, 0, 0);
    }
  };

  auto RDA = [&](int sl, int r) -> h8 {
    return *(const h8*)(smem + sl * 12288 + (r * 4 + (g ^ ((r >> 1) & 3))) * 8);
  };
  auto RDB = [&](int sl, int r) -> h8 {
    return *(const h8*)(smem + sl * 12288 + 4096 + (r * 4 + (g ^ ((r >> 1) & 3))) * 8);
  };

  f4 acc[4][8] = {};
  float pr[4] = {0.f, 0.f, 0.f, 0.f};  // MODE 6: per-A-frag-row partial sums of U
  const int NT = K >> 5;

  STAGE(0, 0);
  STAGE(1, 1);
  vmwait<6>();
  __builtin_amdgcn_s_barrier();

  int sl = 0;
  for (int t = 0; t < NT; ++t) {
    h8 af[4], bf[8];
#pragma unroll
    for (int i = 0; i < 4; ++i) af[i] = RDA(sl, wm * 64 + i * 16 + fr);
#pragma unroll
    for (int j = 0; j < 8; ++j) bf[j] = RDB(sl, wn * 128 + j * 16 + fr);
    if constexpr (MODE == 6) {
#pragma unroll
      for (int i = 0; i < 4; ++i) {
        f16 t0 = (f16)(((af[i][0] + af[i][1]) + (af[i][2] + af[i][3])) +
                       ((af[i][4] + af[i][5]) + (af[i][6] + af[i][7])));
        pr[i] += (float)t0;
      }
    }
    const int ts = (t + 2 < NT) ? t + 2 : NT - 1;
    int ss = sl + 2; if (ss >= 3) ss -= 3;
    STAGE(ss, ts);
    vmwait<6>();                   // tile t+1's 6 loads retired; t+2's in flight
    asm volatile("s_waitcnt lgkmcnt(0)" ::: "memory");
    __builtin_amdgcn_sched_barrier(0);
    __builtin_amdgcn_s_setprio(1);
#pragma unroll
    for (int mi = 0; mi < 4; ++mi)
#pragma unroll
      for (int ni = 0; ni < 8; ++ni)
        acc[mi][ni] = __builtin_amdgcn_mfma_f32_16x16x32_f16(af[mi], bf[ni], acc[mi][ni], 0, 0, 0);
    __builtin_amdgcn_s_setprio(0);
    __builtin_amdgcn_s_barrier();
    sl = (sl + 1 == 3) ? 0 : sl + 1;
  }
  vmwait<0>();   // own tile-DMA drained (incl. clamped tail dups)

  const int fq = g * 4;
  if constexpr (MODE == 1) {
    f16* Cp = (f16*)C;
#pragma unroll
    for (int mi = 0; mi < 4; ++mi)
#pragma unroll
      for (int ni = 0; ni < 8; ++ni)
#pragma unroll
        for (int i = 0; i < 4; ++i) {
          const int row = m0 + wm * 64 + mi * 16 + fq + i;
          const int col = n0 + wn * 128 + ni * 16 + fr;
          Cp[(long)row * N + col] = (f16)(acc[mi][ni][i] * 0.03125f);
        }
  } else if constexpr (MODE == 5) {
    const float* mk = xtra + (long)bz * sC;
    f16* Cp = (f16*)C + (long)bz * sC;
    float* mf = (float*)smem;           // LDS reused: 2 buffers x 8192 f32 = 64 KiB
    __builtin_amdgcn_s_barrier();       // ALL waves' tile-DMA drained before LDS reuse

    // chunk k = mask rows {wm'*64 + k*16 + q} (32 rows x 256 cols = 32 KiB), buf = k&1
    auto MSTAGE = [&](int k, int buf) {
#pragma unroll
      for (int j = 0; j < 8; ++j) {
        const int cr = w * 8 + j;       // 0..31
        const int wmp = cr >> 4, q = cr & 15;
        __builtin_amdgcn_global_load_lds(
            (gchar*)(mk + (long)(m0 + wmp * 64 + k * 16 + q) * N + n0 + (lane << 2)),
            (lchar*)(mf + buf * 8192 + cr * 256 + (lane << 2)), 16, 0, 0);
      }
    };
    MSTAGE(0, 0);
    MSTAGE(1, 1);
    vmwait<8>();                        // chunk 0 retired; chunk 1 in flight
    __builtin_amdgcn_s_barrier();
#pragma unroll
    for (int k = 0; k < 4; ++k) {
      const int buf = k & 1;
      // consume chunk k (accumulator row-block mi = k)
#pragma unroll
      for (int ni = 0; ni < 8; ++ni)
#pragma unroll
        for (int i = 0; i < 4; ++i) {
          const int col = wn * 128 + ni * 16 + fr;
          const float mv = mf[buf * 8192 + (wm * 16 + fq + i) * 256 + col];
          const int row = m0 + wm * 64 + k * 16 + fq + i;
          Cp[(long)row * N + (n0 + col)] = (f16)__expf(acc[k][ni][i] + mv);
        }
      if (k < 3) {
        __builtin_amdgcn_s_barrier();   // all waves done reading buf
        if (k < 2) {
          MSTAGE(k + 2, buf);
          vmwait<8>();                  // chunk k+1 retired; k+2 in flight
        } else {
          vmwait<0>();                  // chunk 3 retired
        }
        __builtin_amdgcn_s_barrier();   // chunk k+1 visible to all waves
      }
    }
  } else {
    // MODE 6: finish rowsums (reduce over g: xor 16,32; gather per-output-row) and divide.
    float* Cp = (float*)C + (long)bz * sC;
#pragma unroll
    for (int mi = 0; mi < 4; ++mi) {
      float sv = pr[mi];
      sv += __shfl_xor(sv, 16);
      sv += __shfl_xor(sv, 32);
#pragma unroll
      for (int i = 0; i < 4; ++i) {
        const float rsv = __shfl(sv, fq + i);
        const float inv = 1.0f / rsv;
        const int row = m0 + wm * 64 + mi * 16 + fq + i;
#pragma unroll
        for (int ni = 0; ni < 8; ++ni) {
          const int col = n0 + wn * 128 + ni * 16 + fr;
          Cp[(long)row * N + col] = acc[mi][ni][i] * inv;
        }
      }
    }
  }
}

extern "C" void kernel_launch(void* const* d_in, const int* in_sizes, int n_in,
                              void* d_out, int out_size, void* d_ws, size_t ws_size,
                              hipStream_t stream) {
  const float* x1 = (const float*)d_in[0];
  const float* x2 = (const float*)d_in[1];
  const float* x3 = (const float*)d_in[2];
  const float* mask = (const float*)d_in[3];
  const float* Wq = (const float*)d_in[4];
  const float* Wk = (const float*)d_in[5];
  const float* Wv = (const float*)d_in[6];

  const long nx = (long)B_ * S_ * D_;
  const long nw = (long)H_ * D_;
  const long nqkv = (long)B_ * S_ * H_;
  const long nsc = (long)B_ * S_ * S_;

  char* ws = (char*)d_ws;
  f16* x1h = (f16*)ws; ws += nx * 2;
  f16* x2h = (f16*)ws; ws += nx * 2;     // scores B-operand
  f16* x3h = (f16*)ws; ws += nx * 2;
  f16* wvh = (f16*)ws; ws += nw * 2;
  f16* wqT = (f16*)ws; ws += nw * 2;
  f16* wkT = (f16*)ws; ws += nw * 2;
  f16* mt  = (f16*)ws; ws += nw * 2;     // Mt[e][d] = sum_h Wk[h][e] Wq[h][d]
  f16* qh  = (f16*)ws; ws += nqkv * 2;   // Qeff = x1 * Mt^T * scale
  f16* vth = (f16*)ws; ws += nqkv * 2;   // V^T [b][h][s]
  f16* sc  = (f16*)ws; ws += nsc * 2;    // U = exp(scores + mask), f16

  prep<<<dim3(8448), 256, 0, stream>>>(x1, x2, x3, Wv, Wq, Wk,
                                       x1h, x2h, x3h, wvh, wqT, wkT);

  const dim3 blk(256);
  // union: V^T projection (256 blocks) + Mt (64 blocks)
  vt_mt<<<dim3(320), blk, 0, stream>>>(x3h, wvh, vth, wkT, wqT, mt);
  // Qeff = x1h * Mt^T * scale : wide tile, 64 x 4 = 256 blocks
  gemm128w<1><<<dim3(256), blk, 0, stream>>>(x1h, mt, qh, nullptr, 1024, 1024,
                                             0, 0, 0, 64, 4);
  // U[b] = exp(Qeff[b] x2[b]^T + mask[b]) -> f16 : 16 x 8 x 4 = 512 blocks
  gemm128w<5><<<dim3(512), blk, 0, stream>>>(qh, x2h, sc, mask, 2048, 1024,
                                             (long)S_ * H_, (long)S_ * D_, (long)S_ * S_, 16, 8);
  // out[b] = (U[b] (V^T[b])^T) / rowsum(U) : 16 x 4 x 4 = 256 blocks, rowsum in-kernel
  gemm128w<6><<<dim3(256), blk, 0, stream>>>(sc, vth, d_out, nullptr, 1024, 2048,
                                             (long)S_ * S_, (long)S_ * H_, (long)S_ * H_, 16, 4);
}